// Round 11
// baseline (439.498 us; speedup 1.0000x reference)
//
#include <hip/hip_runtime.h>

#define DM 256
// (1/sqrt(32)) * log2(e): folded into Q so attn can use exp2
#define QSCALE 0.25503403f

typedef __attribute__((ext_vector_type(8))) short bf16x8;
typedef __attribute__((ext_vector_type(4))) float f32x4;
typedef __attribute__((ext_vector_type(4))) unsigned short us16x4;
typedef __attribute__((ext_vector_type(8))) unsigned short us16x8;
typedef unsigned short us16;

__device__ __forceinline__ unsigned short f2bf(float f) {
  unsigned int u = __float_as_uint(f);
  u += 0x7fffu + ((u >> 16) & 1u);          // round-to-nearest-even
  return (unsigned short)(u >> 16);
}
__device__ __forceinline__ float bf2f(unsigned short s) {
  return __uint_as_float(((unsigned int)s) << 16);
}

__device__ __forceinline__ void gload16(const void* g, void* l) {
  __builtin_amdgcn_global_load_lds(
      (const __attribute__((address_space(1))) void*)g,
      (__attribute__((address_space(3))) void*)l, 16, 0, 0);
}

// ---------------- fused QKV GEMM (one dispatch, grid.z = 0:Q, 1:K, 2:V)
// 128x256 tile, 8 waves (2x4), BK=32, 2-phase double-buffered K-loop.
// Layout REVERTED to [K | V] halves (contiguous stores, no cross-XCD
// partial-line ping-pong): z=1 -> cols 0..255, z=2 -> cols 256..511.
// z=0 output is pre-scaled by QSCALE for the exp2-based softmax.
__global__ __launch_bounds__(512) void qkv_gemm(
    const float* __restrict__ Fa, const float* __restrict__ Fb,
    const us16* __restrict__ W_all, us16* __restrict__ Qbf,
    us16* __restrict__ KVbf, int NA, int NB)
{
  const int z = blockIdx.z;
  const float* A = (z == 0) ? Fa : Fb;
  const int Mreal = (z == 0) ? NA : NB;
  const int Mp = (Mreal + 127) & ~127;
  const us16* W = W_all + (size_t)z * 256 * 256;
  us16* Cb = (z == 0) ? Qbf : KVbf;
  const int ldc = (z == 0) ? 256 : 512;
  const int colofs = (z == 2) ? 256 : 0;

  __shared__ us16 As[2][128 * 32];
  __shared__ us16 Bs[2][256 * 32];
  const int tid = threadIdx.x;
  const int w = tid >> 6, l = tid & 63;
  const int wr = w >> 2, wc = w & 3;          // wave grid 2 x 4
  const int rowBase = blockIdx.x * 128;
  if (rowBase >= Mp) return;
  const int ar = tid >> 2, ac = (tid & 3) * 8;
  const int grow0 = rowBase + ar;
  const bool aval = grow0 < Mreal;
  const float* Ap = A + (size_t)grow0 * 256 + ac;
  f32x4 acc[4][4] = {};

  // prologue: stage k0=0 into buffer 0
  {
    float4 x = make_float4(0.f, 0.f, 0.f, 0.f), y = x;
    if (aval) { x = *(const float4*)(Ap); y = *(const float4*)(Ap + 4); }
#pragma unroll
    for (int j = 0; j < 2; ++j) {
      const int r0 = (w * 2 + j) * 16;
      gload16(W + (size_t)(r0 + (l >> 2)) * 256 + (l & 3) * 8, &Bs[0][r0 * 32]);
    }
    bf16x8 av;
    av[0] = (short)f2bf(x.x); av[1] = (short)f2bf(x.y);
    av[2] = (short)f2bf(x.z); av[3] = (short)f2bf(x.w);
    av[4] = (short)f2bf(y.x); av[5] = (short)f2bf(y.y);
    av[6] = (short)f2bf(y.z); av[7] = (short)f2bf(y.w);
    *(bf16x8*)&As[0][ar * 32 + ac] = av;
  }
  __syncthreads();

  for (int t = 0; t < 8; ++t) {
    const int cur = t & 1, nxt = cur ^ 1;
    const bool pf = (t < 7);
    float4 x, y;
    if (pf) {
      const int k0 = (t + 1) * 32;
      x = make_float4(0.f, 0.f, 0.f, 0.f); y = x;
      if (aval) { x = *(const float4*)(Ap + k0); y = *(const float4*)(Ap + k0 + 4); }
#pragma unroll
      for (int j = 0; j < 2; ++j) {
        const int r0 = (w * 2 + j) * 16;
        gload16(W + (size_t)(r0 + (l >> 2)) * 256 + k0 + (l & 3) * 8,
                &Bs[nxt][r0 * 32]);
      }
    }
    bf16x8 af[4], bfr[4];
#pragma unroll
    for (int m = 0; m < 4; ++m)
      af[m] = *(const bf16x8*)&As[cur][(wr * 64 + m * 16 + (l & 15)) * 32 + (l >> 4) * 8];
#pragma unroll
    for (int n = 0; n < 4; ++n)
      bfr[n] = *(const bf16x8*)&Bs[cur][(wc * 64 + n * 16 + (l & 15)) * 32 + (l >> 4) * 8];
#pragma unroll
    for (int m = 0; m < 4; ++m)
#pragma unroll
      for (int n = 0; n < 4; ++n)
        acc[m][n] = __builtin_amdgcn_mfma_f32_16x16x32_bf16(af[m], bfr[n], acc[m][n], 0, 0, 0);
    if (pf) {
      bf16x8 av;
      av[0] = (short)f2bf(x.x); av[1] = (short)f2bf(x.y);
      av[2] = (short)f2bf(x.z); av[3] = (short)f2bf(x.w);
      av[4] = (short)f2bf(y.x); av[5] = (short)f2bf(y.y);
      av[6] = (short)f2bf(y.z); av[7] = (short)f2bf(y.w);
      *(bf16x8*)&As[nxt][ar * 32 + ac] = av;
    }
    __syncthreads();
  }

  // epilogue: C/D layout col=lane&15, row=(lane>>4)*4+j  [m89-verified]
  const int er = (l >> 4) * 4;
  const int ec = l & 15;
#pragma unroll
  for (int m = 0; m < 4; ++m)
#pragma unroll
    for (int n = 0; n < 4; ++n)
#pragma unroll
      for (int j = 0; j < 4; ++j) {
        const int grow = rowBase + wr * 64 + m * 16 + er + j;
        const int c = wc * 64 + n * 16 + ec;          // local col 0..255
        float v = acc[m][n][j];
        if (z == 0) v *= QSCALE;
        Cb[(size_t)grow * ldc + c + colofs] = f2bf(v);
      }
}

// ---------------- proj GEMM: C = A(bf16) @ Wp^T + R, fp32 out, row-guarded
// 2-phase double-buffered; both A and B via global_load_lds.
__global__ __launch_bounds__(512) void proj_gemm(
    const us16* __restrict__ A, const us16* __restrict__ W,
    float* __restrict__ Cf, const float* __restrict__ R, int Mreal)
{
  __shared__ us16 As[2][128 * 32];
  __shared__ us16 Bs[2][256 * 32];
  const int tid = threadIdx.x;
  const int w = tid >> 6, l = tid & 63;
  const int wr = w >> 2, wc = w & 3;
  const int rowBase = blockIdx.x * 128;
  f32x4 acc[4][4] = {};

  // prologue: stage k0=0 into buffer 0
  {
    const int r0 = w * 16;                 // A: 8 waves x 16 rows
    gload16(A + (size_t)(rowBase + r0 + (l >> 2)) * 256 + (l & 3) * 8,
            &As[0][r0 * 32]);
#pragma unroll
    for (int j = 0; j < 2; ++j) {
      const int rb = (w * 2 + j) * 16;
      gload16(W + (size_t)(rb + (l >> 2)) * 256 + (l & 3) * 8, &Bs[0][rb * 32]);
    }
  }
  __syncthreads();

  for (int t = 0; t < 8; ++t) {
    const int cur = t & 1, nxt = cur ^ 1;
    if (t < 7) {
      const int k0 = (t + 1) * 32;
      const int r0 = w * 16;
      gload16(A + (size_t)(rowBase + r0 + (l >> 2)) * 256 + k0 + (l & 3) * 8,
              &As[nxt][r0 * 32]);
#pragma unroll
      for (int j = 0; j < 2; ++j) {
        const int rb = (w * 2 + j) * 16;
        gload16(W + (size_t)(rb + (l >> 2)) * 256 + k0 + (l & 3) * 8,
                &Bs[nxt][rb * 32]);
      }
    }
    bf16x8 af[4], bfr[4];
#pragma unroll
    for (int m = 0; m < 4; ++m)
      af[m] = *(const bf16x8*)&As[cur][(wr * 64 + m * 16 + (l & 15)) * 32 + (l >> 4) * 8];
#pragma unroll
    for (int n = 0; n < 4; ++n)
      bfr[n] = *(const bf16x8*)&Bs[cur][(wc * 64 + n * 16 + (l & 15)) * 32 + (l >> 4) * 8];
#pragma unroll
    for (int m = 0; m < 4; ++m)
#pragma unroll
      for (int n = 0; n < 4; ++n)
        acc[m][n] = __builtin_amdgcn_mfma_f32_16x16x32_bf16(af[m], bfr[n], acc[m][n], 0, 0, 0);
    __syncthreads();
  }

  const int er = (l >> 4) * 4;
  const int ec = l & 15;
#pragma unroll
  for (int m = 0; m < 4; ++m)
#pragma unroll
    for (int n = 0; n < 4; ++n)
#pragma unroll
      for (int j = 0; j < 4; ++j) {
        const int grow = rowBase + wr * 64 + m * 16 + er + j;
        if (grow < Mreal) {
          const size_t off = (size_t)grow * 256 + wc * 64 + n * 16 + ec;
          Cf[off] = acc[m][n][j] + R[off];
        }
      }
}

// ---------------- all 4 weight matrices -> one bf16 [1024 x 256] buffer
__global__ void cvt_weights(const float* __restrict__ Wq, const float* __restrict__ Wk,
                            const float* __restrict__ Wv, const float* __restrict__ Wp,
                            us16* __restrict__ out)
{
  const int g = blockIdx.x * 256 + threadIdx.x;      // 32768 threads
  const size_t e = (size_t)g * 8;
  const int sel = (int)(e >> 16);
  const float* src = (sel == 0) ? Wq : (sel == 1) ? Wk : (sel == 2) ? Wv : Wp;
  const size_t loc = e & 65535;
  const float4 x = *(const float4*)(src + loc);
  const float4 y = *(const float4*)(src + loc + 4);
  bf16x8 o;
  o[0] = (short)f2bf(x.x); o[1] = (short)f2bf(x.y);
  o[2] = (short)f2bf(x.z); o[3] = (short)f2bf(x.w);
  o[4] = (short)f2bf(y.x); o[5] = (short)f2bf(y.y);
  o[6] = (short)f2bf(y.z); o[7] = (short)f2bf(y.w);
  *(bf16x8*)(out + e) = o;
}

// ---------------- CSR build ----------------
__global__ void hist_kernel(const int* __restrict__ a_idx, int* __restrict__ counts, int E)
{
  const int e = blockIdx.x * 256 + threadIdx.x;
  if (e < E) atomicAdd(&counts[a_idx[e]], 1);
}

__global__ __launch_bounds__(256) void scan_offs(const int* __restrict__ counts,
    int* __restrict__ offs, int* __restrict__ cursor, int* __restrict__ total, int n)
{
  __shared__ int buf[256];
  __shared__ int sbase;
  const int t = threadIdx.x;
  const int i = blockIdx.x * 256 + t;
  const int v = (i < n) ? counts[i] : 0;
  buf[t] = v;
  __syncthreads();
#pragma unroll
  for (int off = 1; off < 256; off <<= 1) {
    const int x = (t >= off) ? buf[t - off] : 0;
    __syncthreads();
    buf[t] += x;
    __syncthreads();
  }
  const int incl = buf[t];
  if (t == 255) sbase = atomicAdd(total, incl);
  __syncthreads();
  if (i < n) {
    const int excl = sbase + incl - v;
    offs[i] = excl;
    cursor[i] = excl;
  }
}

__global__ void scatter_kernel(const int* __restrict__ a_idx, const int* __restrict__ b_idx,
    int* __restrict__ cursor, int* __restrict__ bel, int E)
{
  const int e = blockIdx.x * 256 + threadIdx.x;
  if (e < E) bel[atomicAdd(&cursor[a_idx[e]], 1)] = b_idx[e];
}

// ---------------- edge attention: TWO NODES PER WAVE, 4 lanes/head, 8 dims/lane.
// lanes 0-31 = node a0, lanes 32-63 = node a1; within a half: h=(hd>>2), dims
// (hd&3)*8.. One us16x8 K load per lane = wave covers both nodes' full K rows
// (2 x 512 B contiguous). Dot = 8 fma + 2 shuffles. Q pre-scaled -> exp2.
#define ATTN_STEP(K, V, J)                                     \
  if ((J) < cnt) {                                             \
    float p = q0 * bf2f(K[0]);                                 \
    p = fmaf(q1, bf2f(K[1]), p);                               \
    p = fmaf(q2, bf2f(K[2]), p);                               \
    p = fmaf(q3, bf2f(K[3]), p);                               \
    p = fmaf(q4, bf2f(K[4]), p);                               \
    p = fmaf(q5, bf2f(K[5]), p);                               \
    p = fmaf(q6, bf2f(K[6]), p);                               \
    p = fmaf(q7, bf2f(K[7]), p);                               \
    p += __shfl_xor(p, 1, 64);                                 \
    p += __shfl_xor(p, 2, 64);                                 \
    const float ex = exp2f(p);                                 \
    ssum += ex;                                                \
    acc0 = fmaf(ex, bf2f(V[0]), acc0);                         \
    acc1 = fmaf(ex, bf2f(V[1]), acc1);                         \
    acc2 = fmaf(ex, bf2f(V[2]), acc2);                         \
    acc3 = fmaf(ex, bf2f(V[3]), acc3);                         \
    acc4 = fmaf(ex, bf2f(V[4]), acc4);                         \
    acc5 = fmaf(ex, bf2f(V[5]), acc5);                         \
    acc6 = fmaf(ex, bf2f(V[6]), acc6);                         \
    acc7 = fmaf(ex, bf2f(V[7]), acc7);                         \
  }

#define ATTN_LOAD(K, V, IDX)                                   \
  {                                                            \
    const us16* kv = KVb + (size_t)bel[sstart + (IDX)] * 512 + kvo; \
    K = *(const us16x8*)(kv);                                  \
    V = *(const us16x8*)(kv + 256);                            \
  }

__global__ __launch_bounds__(256) void edge_attn(
    const us16* __restrict__ Qb, const us16* __restrict__ KVb,
    const int* __restrict__ offs, const int* __restrict__ counts,
    const int* __restrict__ bel, us16* __restrict__ outb, int NA)
{
  const int a = blockIdx.x * 8 + (threadIdx.x >> 5);
  const int hd = threadIdx.x & 31;
  const int kvo = hd * 8;                   // head*32 + dgrp*8 == hd*8
  const bool valid = (a < NA);

  const int aa = valid ? a : (NA - 1);
  const us16x8 q8 = *(const us16x8*)(Qb + (size_t)aa * 256 + kvo);
  const float q0 = bf2f(q8[0]), q1 = bf2f(q8[1]), q2 = bf2f(q8[2]), q3 = bf2f(q8[3]);
  const float q4 = bf2f(q8[4]), q5 = bf2f(q8[5]), q6 = bf2f(q8[6]), q7 = bf2f(q8[7]);

  const int cnt = valid ? counts[a] : 0;
  const int sstart = (cnt > 0) ? offs[a] : 0;
  const int last = (cnt > 0) ? cnt - 1 : 0;
  // wave-max count across the two halves (shfl from exited lanes avoided:
  // no lane exits before this point)
  const int mcnt = max(cnt, __shfl_xor(cnt, 32, 64));

  float acc0 = 0.f, acc1 = 0.f, acc2 = 0.f, acc3 = 0.f;
  float acc4 = 0.f, acc5 = 0.f, acc6 = 0.f, acc7 = 0.f;
  float ssum = 0.f;

  if (mcnt > 0) {
    us16x8 ka, va, kb, vb, kc, vc, kd, vd;
    ATTN_LOAD(ka, va, 0)
    ATTN_LOAD(kb, vb, min(1, last))
    ATTN_LOAD(kc, vc, min(2, last))
    ATTN_LOAD(kd, vd, min(3, last))
    for (int i = 0; i < mcnt; i += 4) {
      us16x8 na, xa, nb, xb, nc, xc, nd, xd;
      ATTN_LOAD(na, xa, min(i + 4, last))
      ATTN_LOAD(nb, xb, min(i + 5, last))
      ATTN_LOAD(nc, xc, min(i + 6, last))
      ATTN_LOAD(nd, xd, min(i + 7, last))
      ATTN_STEP(ka, va, i + 0)
      ATTN_STEP(kb, vb, i + 1)
      ATTN_STEP(kc, vc, i + 2)
      ATTN_STEP(kd, vd, i + 3)
      ka = na; va = xa; kb = nb; vb = xb;
      kc = nc; vc = xc; kd = nd; vd = xd;
    }
  }

  if (valid) {
    const float inv = (cnt > 0) ? 1.f / ssum : 0.f;
    us16x8 o;
    o[0] = (short)f2bf(acc0 * inv); o[1] = (short)f2bf(acc1 * inv);
    o[2] = (short)f2bf(acc2 * inv); o[3] = (short)f2bf(acc3 * inv);
    o[4] = (short)f2bf(acc4 * inv); o[5] = (short)f2bf(acc5 * inv);
    o[6] = (short)f2bf(acc6 * inv); o[7] = (short)f2bf(acc7 * inv);
    *(us16x8*)(outb + (size_t)a * 256 + kvo) = o;
  }
}

extern "C" void kernel_launch(void* const* d_in, const int* in_sizes, int n_in,
                              void* d_out, int out_size, void* d_ws, size_t ws_size,
                              hipStream_t stream)
{
  const float* Fa    = (const float*)d_in[0];
  const float* Fb    = (const float*)d_in[1];
  const int*   a_idx = (const int*)d_in[2];
  const int*   b_idx = (const int*)d_in[3];
  const float* Wq    = (const float*)d_in[4];
  const float* Wk    = (const float*)d_in[5];
  const float* Wv    = (const float*)d_in[6];
  const float* Wproj = (const float*)d_in[7];
  float* out = (float*)d_out;

  const int NA = in_sizes[0] / DM;
  const int NB = in_sizes[1] / DM;
  const int E  = in_sizes[2];
  const int MAp = (NA + 127) & ~127;
  const int NBp = (NB + 127) & ~127;
  const int MXp = (MAp > NBp) ? MAp : NBp;

  // workspace: Qbf | KVbf | ATbf | W_all | ints
  us16* Qbf   = (us16*)d_ws;                        // MAp*256 (pre-scaled)
  us16* KVbf  = Qbf   + (size_t)MAp * 256;          // NBp*512 ([K | V] halves)
  us16* ATbf  = KVbf  + (size_t)NBp * 512;          // MAp*256
  us16* W_all = ATbf  + (size_t)MAp * 256;          // 1024*256: [Wq;Wk;Wv;Wp]
  int* total  = (int*)(W_all + 1024 * 256);
  int* counts = total + 1;
  int* offs   = counts + NA;
  int* cursor = offs + NA;
  int* bel    = cursor + NA;

  hipMemsetAsync(total, 0, (size_t)(NA + 1) * sizeof(int), stream);

  cvt_weights<<<128, 256, 0, stream>>>(Wq, Wk, Wv, Wproj, W_all);

  // CSR build
  hist_kernel<<<(E + 255) / 256, 256, 0, stream>>>(a_idx, counts, E);
  scan_offs<<<(NA + 255) / 256, 256, 0, stream>>>(counts, offs, cursor, total, NA);
  scatter_kernel<<<(E + 255) / 256, 256, 0, stream>>>(a_idx, b_idx, cursor, bel, E);

  // fused Q/K/V projections (one dispatch, z = 0/1/2)
  qkv_gemm<<<dim3(MXp / 128, 1, 3), 512, 0, stream>>>(Fa, Fb, W_all, Qbf, KVbf, NA, NB);

  // attention: two nodes per wave, 8 nodes per block
  edge_attn<<<(NA + 7) / 8, 256, 0, stream>>>(Qbf, KVbf, offs, counts, bel, ATbf, NA);

  // output projection + residual (fp32 out, guarded)
  proj_gemm<<<dim3(MAp / 128, 1), 512, 0, stream>>>(ATbf, W_all + 768 * 256, out, Fa, NA);
}